// Round 7
// baseline (194.285 us; speedup 1.0000x reference)
//
#include <hip/hip_runtime.h>

#define EPS 1e-5f

typedef _Float16 half8 __attribute__((ext_vector_type(8)));
typedef _Float16 half4 __attribute__((ext_vector_type(4)));
typedef float f32x16 __attribute__((ext_vector_type(16)));
typedef float f32x4v __attribute__((ext_vector_type(4)));

// Fragment layout for an [R x K] f16 matrix consumed as 32-row MFMA operand:
// element (row, k) -> ((row>>5)*(K/16) + (k>>4))*512 + ((k>>3)&1)*256 + (row&31)*8 + (k&7)
// wave fragment load for (rowgroup rg, kslice ks) = base + (rg*(K/16)+ks)*512 + lane*8
// = 64 lanes x 16 B contiguous (perfectly coalesced).

// ---------------------------------------------------------------------------
// pre_kernel: blocks 0..255 = hxhy via MFMA (w1 consumed directly, alpha/bias
// folded in epilogue; hy written in fragment layout); blocks 256..319 =
// weight prep (BN-fold w2/w3, cast w4; all written in fragment layout).
// ---------------------------------------------------------------------------
__global__ __launch_bounds__(256)
void pre_kernel(
    const float* __restrict__ x, const float* __restrict__ y,
    const float* __restrict__ w1, const float* __restrict__ b1,
    const float* __restrict__ g1, const float* __restrict__ be1,
    const float* __restrict__ m1, const float* __restrict__ v1,
    const float* __restrict__ w2, const float* __restrict__ b2,
    const float* __restrict__ g2, const float* __restrict__ be2,
    const float* __restrict__ m2, const float* __restrict__ v2,
    const float* __restrict__ w3, const float* __restrict__ b3,
    const float* __restrict__ g3, const float* __restrict__ be3,
    const float* __restrict__ m3, const float* __restrict__ v3,
    const float* __restrict__ w4,
    _Float16* __restrict__ hxh, _Float16* __restrict__ hyh,
    _Float16* __restrict__ w2h, _Float16* __restrict__ w3h,
    _Float16* __restrict__ w4h,
    float* __restrict__ b2f, float* __restrict__ b3f)
{
    const int t = threadIdx.x;

    if (blockIdx.x >= 256) {
        // ---------------- prep part (fragment-scattered writes) ----------------
        int tid = (blockIdx.x - 256) * 256 + t;
        const int nth = 64 * 256;
        for (int idx = tid; idx < 256 * 512; idx += nth) {
            int n = idx >> 9, k = idx & 511;
            float a = g2[n] * rsqrtf(v2[n] + EPS);
            int addr = ((n >> 5) * 32 + (k >> 4)) * 512 + ((k >> 3) & 1) * 256 + (n & 31) * 8 + (k & 7);
            w2h[addr] = (_Float16)(a * w2[idx]);
        }
        for (int idx = tid; idx < 128 * 256; idx += nth) {
            int n = idx >> 8, k = idx & 255;
            float a = g3[n] * rsqrtf(v3[n] + EPS);
            int addr = ((n >> 5) * 16 + (k >> 4)) * 512 + ((k >> 3) & 1) * 256 + (n & 31) * 8 + (k & 7);
            w3h[addr] = (_Float16)(a * w3[idx]);
        }
        for (int idx = tid; idx < 64 * 128; idx += nth) {
            int n = idx >> 7, k = idx & 127;
            int addr = ((n >> 5) * 8 + (k >> 4)) * 512 + ((k >> 3) & 1) * 256 + (n & 31) * 8 + (k & 7);
            w4h[addr] = (_Float16)w4[idx];
        }
        if (tid < 256) {
            float a = g2[tid] * rsqrtf(v2[tid] + EPS);
            b2f[tid] = a * b2[tid] + be2[tid] - m2[tid] * a;
        } else if (tid < 384) {
            int n = tid - 256;
            float a = g3[n] * rsqrtf(v3[n] + EPS);
            b3f[n] = a * b3[n] + be3[n] - m3[n] * a;
        }
        return;
    }

    // ---------------- hxhy part ----------------
    // bid: rg = 32-row group (32), ng = 128-col group (4), which = x/y (2)
    const int rg = blockIdx.x & 31;
    const int ng = (blockIdx.x >> 5) & 3;
    const int which = blockIdx.x >> 7;

    constexpr int LDA = 136;  // 272 B row stride
    __shared__ _Float16 sh[32 * 136 + 128 * 136] __attribute__((aligned(16)));
    _Float16* xa = sh;                 // [32][136]
    _Float16* wb = sh + 32 * 136;      // [128][136]

    const int rowbase = rg * 32;
    const float* src = which ? y : x;

    // stage A: 32 rows x 128 f32 -> f16
#pragma unroll
    for (int p = 0; p < 4; ++p) {
        int c = p * 256 + t;               // 0..1023 float4-chunks
        int r = c >> 5, fo = (c & 31) * 4;
        f32x4v v = *(const f32x4v*)(src + (size_t)(rowbase + r) * 128 + fo);
        half4 h; h[0] = (_Float16)v[0]; h[1] = (_Float16)v[1];
        h[2] = (_Float16)v[2]; h[3] = (_Float16)v[3];
        *(half4*)(xa + r * LDA + fo) = h;
    }
    // stage B: 128 n-rows x 128 k f32 -> f16 (w1 row-major, k-offset by which)
#pragma unroll
    for (int p = 0; p < 16; ++p) {
        int c = p * 256 + t;               // 0..4095
        int n = c >> 5, fo = (c & 31) * 4;
        f32x4v v = *(const f32x4v*)(w1 + (size_t)(ng * 128 + n) * 256 + which * 128 + fo);
        half4 h; h[0] = (_Float16)v[0]; h[1] = (_Float16)v[1];
        h[2] = (_Float16)v[2]; h[3] = (_Float16)v[3];
        *(half4*)(wb + n * LDA + fo) = h;
    }
    __syncthreads();

    const int wid = t >> 6;
    const int l = t & 63;
    const int l31 = l & 31, lh = l >> 5;

    f32x16 acc = (f32x16)0.f;
#pragma unroll
    for (int kc = 0; kc < 8; ++kc) {
        half8 af = *(const half8*)(xa + l31 * LDA + kc * 16 + lh * 8);
        half8 bf = *(const half8*)(wb + (wid * 32 + l31) * LDA + kc * 16 + lh * 8);
        acc = __builtin_amdgcn_mfma_f32_32x32x16_f16(af, bf, acc, 0, 0, 0);
    }

    const int n = ng * 128 + wid * 32 + l31;
    float alpha = g1[n] * rsqrtf(v1[n] + EPS);
    if (which == 0) {
        float bias = alpha * b1[n] + be1[n] - m1[n] * alpha;
#pragma unroll
        for (int r = 0; r < 16; ++r) {
            int m = (r & 3) + 8 * (r >> 2) + 4 * lh;
            hxh[(size_t)(rowbase + m) * 512 + n] = (_Float16)(alpha * acc[r] + bias);
        }
    } else {
        // hy in fragment layout (per-b region of 65536 halves; K16=32)
        const int ks = n >> 4, lhh = (n >> 3) & 1, c = n & 7;
#pragma unroll
        for (int r = 0; r < 16; ++r) {
            int m = (r & 3) + 8 * (r >> 2) + 4 * lh;
            int R = rowbase + m;                // global row = b*128 + j
            int bb = R >> 7, j = R & 127;
            int addr = bb * 65536 + ((j >> 5) * 32 + ks) * 512 + lhh * 256 + (j & 31) * 8 + c;
            hyh[addr] = (_Float16)(alpha * acc[r]);
        }
    }
}

// ---------------------------------------------------------------------------
// fused: one block per (b,i). M=128 (all j), 512->256->128->64 MLP with
// 32x32x16 f16 MFMA, then s=sum_j e, out[j]=e[j]·s. 512 threads = 8 waves.
// L2 phase: 4M x 2N wave grid (each row-group assembled by only 2 waves ->
// half the relu VALU), A/B fragments streamed directly from global
// (pre-swizzled fragment layout, L2-resident), bias folded into MFMA C-init.
// L3/L4 keep proven 0-conflict LDS form. LDS 71168 B -> 2 blocks/CU.
// ---------------------------------------------------------------------------
__global__ __launch_bounds__(512, 4)
void fused_kernel(
    const _Float16* __restrict__ hxh, const _Float16* __restrict__ hyh,
    const _Float16* __restrict__ w2h, const _Float16* __restrict__ w3h,
    const _Float16* __restrict__ w4h,
    const float* __restrict__ b2f, const float* __restrict__ b3f,
    const float* __restrict__ b4,
    float* __restrict__ out)
{
    constexpr int LD2 = 264;  // a2 row stride (halves), 528 B (proven 0-conflict)
    constexpr int LD3 = 136;  // a3 row stride (halves), 272 B
    constexpr int LDE = 68;   // es row stride (f32), 272 B

    __shared__ char smem[3584 + 67584] __attribute__((aligned(16)));
    _Float16* hxs = (_Float16*)smem;             // [512] f16   1024 B
    float* spart  = (float*)(smem + 1024);       // [8][64]     2048 B
    float* ss     = (float*)(smem + 3072);       // [64]         256 B
    char* R1 = smem + 3584;
    _Float16* a2  = (_Float16*)R1;               // [128][264] 67584 B (after L2)
    _Float16* a3  = (_Float16*)R1;               // [128][136] (after L3)
    float*    es  = (float*)R1;                  // [128][68]  (after L4)

    const int b = blockIdx.x >> 7;
    const int i = blockIdx.x & 127;
    const int t = threadIdx.x;
    const int wid = t >> 6;
    const int l   = t & 63;
    const int l31 = l & 31;
    const int lh  = l >> 5;

    if (t < 64)
        *(half8*)(hxs + t * 8) = *(const half8*)(hxh + (size_t)(b * 128 + i) * 512 + t * 8);
    __syncthreads();

    // ---------------- layer 2: [128x512] @ [256x512]^T, 4M x 2N ----------------
    const int wm2 = wid >> 1;                    // 0..3 row-group (32 rows)
    const int wn2 = wid & 1;                     // 0..1 col-half (128 cols)

    const _Float16* pa = hyh + (size_t)b * 65536 + (size_t)(wm2 * 32) * 512 + l * 8;
    const _Float16* pb = w2h + (size_t)(wn2 * 4) * 32 * 512 + l * 8;

    f32x16 acc2[4];
#pragma unroll
    for (int nt = 0; nt < 4; ++nt)
        acc2[nt] = (f32x16)(b2f[wn2 * 128 + nt * 32 + l31]);   // bias C-init

    auto LDA_ = [&](half8& A, int ks) {
        A = *(const half8*)(pa + ks * 512);
    };
    auto LDB_ = [&](half8 (&B)[4], int ks) {
#pragma unroll
        for (int nt = 0; nt < 4; ++nt)
            B[nt] = *(const half8*)(pb + (size_t)(nt * 32 + ks) * 512);
    };
    auto STEP = [&](half8 A, half8 (&B)[4], int ks) {
        half8 rx = *(const half8*)(hxs + ks * 16 + lh * 8);
        half8 s = A + rx;
        half8 af;
#pragma unroll
        for (int c = 0; c < 8; ++c)
            af[c] = s[c] > (_Float16)0.f ? s[c] : (_Float16)0.f;
#pragma unroll
        for (int nt = 0; nt < 4; ++nt)
            acc2[nt] = __builtin_amdgcn_mfma_f32_32x32x16_f16(af, B[nt], acc2[nt], 0, 0, 0);
    };

    {
        half8 A0, A1, B0[4], B1[4];
        LDA_(A0, 0); LDB_(B0, 0);
#pragma unroll
        for (int ks = 0; ks < 32; ks += 2) {
            if (ks + 1 < 32) { LDA_(A1, ks + 1); LDB_(B1, ks + 1); }
            STEP(A0, B0, ks);
            if (ks + 2 < 32) { LDA_(A0, ks + 2); LDB_(B0, ks + 2); }
            if (ks + 1 < 32) STEP(A1, B1, ks + 1);
        }
    }

    // epilogue -> a2 (fp16, relu); bias already in acc
#pragma unroll
    for (int nt = 0; nt < 4; ++nt)
#pragma unroll
        for (int r = 0; r < 16; ++r) {
            int m = wm2 * 32 + (r & 3) + 8 * (r >> 2) + 4 * lh;
            a2[m * LD2 + wn2 * 128 + nt * 32 + l31] = (_Float16)fmaxf(acc2[nt][r], 0.f);
        }
    __syncthreads();

    // ---------------- layer 3: [128x256] @ [128x256]^T, B = global fragments ----
    const int wm = wid >> 2, wn = wid & 3;       // 2 x 4 wave grid
    f32x16 acc3[2];
    {
        float b3v = b3f[wn * 32 + l31];          // bias C-init
        acc3[0] = (f32x16)b3v;
        acc3[1] = (f32x16)b3v;
    }
#pragma unroll 8
    for (int kc = 0; kc < 16; ++kc) {
        half8 bfr = *(const half8*)(w3h + (wn * 16 + kc) * 512 + l * 8);
        half8 af0 = *(const half8*)(a2 + (wm * 64 + l31) * LD2 + kc * 16 + lh * 8);
        half8 af1 = *(const half8*)(a2 + (wm * 64 + 32 + l31) * LD2 + kc * 16 + lh * 8);
        acc3[0] = __builtin_amdgcn_mfma_f32_32x32x16_f16(af0, bfr, acc3[0], 0, 0, 0);
        acc3[1] = __builtin_amdgcn_mfma_f32_32x32x16_f16(af1, bfr, acc3[1], 0, 0, 0);
    }
    __syncthreads();
#pragma unroll
    for (int mt = 0; mt < 2; ++mt)
#pragma unroll
        for (int r = 0; r < 16; ++r) {
            int m = wm * 64 + mt * 32 + (r & 3) + 8 * (r >> 2) + 4 * lh;
            a3[m * LD3 + wn * 32 + l31] = (_Float16)fmaxf(acc3[mt][r], 0.f);
        }
    __syncthreads();

    // ---------------- layer 4: [128x128] @ [64x128]^T, regrid 4x2 ----------
    const int wm4 = wid >> 1, wn4 = wid & 1;
    f32x16 acc4 = (f32x16)(b4[wn4 * 32 + l31]);  // bias C-init
#pragma unroll
    for (int kc = 0; kc < 8; ++kc) {
        half8 afr = *(const half8*)(a3 + (wm4 * 32 + l31) * LD3 + kc * 16 + lh * 8);
        half8 bfr = *(const half8*)(w4h + (wn4 * 8 + kc) * 512 + l * 8);
        acc4 = __builtin_amdgcn_mfma_f32_32x32x16_f16(afr, bfr, acc4, 0, 0, 0);
    }
    __syncthreads();  // a3 reads done before es overwrites it
#pragma unroll
    for (int r = 0; r < 16; ++r) {
        int m = wm4 * 32 + (r & 3) + 8 * (r >> 2) + 4 * lh;
        es[m * LDE + wn4 * 32 + l31] = acc4[r];
    }
    __syncthreads();

    // ---------------- s = sum_j e ; out[j] = sum_k e[j][k]*s[k] ------------
    {
        float sv = 0.f;
#pragma unroll
        for (int jj = 0; jj < 16; ++jj) sv += es[(wid + jj * 8) * LDE + l];
        spart[wid * 64 + l] = sv;
    }
    __syncthreads();
    if (t < 64) {
        float s2 = 0.f;
#pragma unroll
        for (int r = 0; r < 8; ++r) s2 += spart[r * 64 + t];
        ss[t] = s2;
    }
    __syncthreads();
    {
        const int j = t >> 2, q = t & 3;
        float p = 0.f;
#pragma unroll
        for (int c = 0; c < 16; ++c) {
            int k = q + 4 * c;               // k-interleaved: 2 lanes/bank
            p += es[j * LDE + k] * ss[k];
        }
        p += __shfl_xor(p, 1);
        p += __shfl_xor(p, 2);
        if (q == 0) out[(size_t)(b * 128 + i) * 128 + j] = p;
    }
}

// ---------------------------------------------------------------------------
extern "C" void kernel_launch(void* const* d_in, const int* in_sizes, int n_in,
                              void* d_out, int out_size, void* d_ws, size_t ws_size,
                              hipStream_t stream)
{
    (void)in_sizes; (void)n_in; (void)out_size; (void)ws_size;

    const float* x   = (const float*)d_in[0];
    const float* y   = (const float*)d_in[1];
    const float* w1  = (const float*)d_in[2];
    const float* b1  = (const float*)d_in[3];
    const float* g1  = (const float*)d_in[4];
    const float* be1 = (const float*)d_in[5];
    const float* m1  = (const float*)d_in[6];
    const float* v1  = (const float*)d_in[7];
    const float* w2  = (const float*)d_in[8];
    const float* b2  = (const float*)d_in[9];
    const float* g2  = (const float*)d_in[10];
    const float* be2 = (const float*)d_in[11];
    const float* m2  = (const float*)d_in[12];
    const float* v2  = (const float*)d_in[13];
    const float* w3  = (const float*)d_in[14];
    const float* b3  = (const float*)d_in[15];
    const float* g3  = (const float*)d_in[16];
    const float* be3 = (const float*)d_in[17];
    const float* m3  = (const float*)d_in[18];
    const float* v3  = (const float*)d_in[19];
    const float* w4  = (const float*)d_in[20];
    const float* b4  = (const float*)d_in[21];
    float* out = (float*)d_out;

    // workspace layout (~2.44 MB)
    float* b2f = (float*)d_ws;                 // 256 f32
    float* b3f = b2f + 256;                    // 128 f32
    _Float16* w2h = (_Float16*)(b3f + 128);    // 131072 f16 (fragment layout)
    _Float16* w3h = w2h + 131072;              // 32768 f16  (fragment layout)
    _Float16* w4h = w3h + 32768;               // 8192 f16   (fragment layout)
    _Float16* hxh = w4h + 8192;                // 524288 f16 (linear)
    _Float16* hyh = hxh + 524288;              // 524288 f16 (fragment layout per b)

    hipLaunchKernelGGL(pre_kernel, dim3(320), dim3(256), 0, stream,
                       x, y, w1, b1, g1, be1, m1, v1,
                       w2, b2, g2, be2, m2, v2,
                       w3, b3, g3, be3, m3, v3,
                       w4,
                       hxh, hyh, w2h, w3h, w4h, b2f, b3f);

    hipLaunchKernelGGL(fused_kernel, dim3(1024), dim3(512), 0, stream,
                       hxh, hyh, w2h, w3h, w4h, b2f, b3f, b4, out);
}

// Round 8
// 68.840 us; speedup vs baseline: 2.8223x; 2.8223x over previous
//
#include <hip/hip_runtime.h>

#define EPS 1e-5f

typedef _Float16 half8 __attribute__((ext_vector_type(8)));
typedef _Float16 half4 __attribute__((ext_vector_type(4)));
typedef float f32x16 __attribute__((ext_vector_type(16)));
typedef float f32x4v __attribute__((ext_vector_type(4)));

// Fragment layout for an [R x K] f16 matrix consumed as 32-row MFMA operand:
// element (row, k) -> ((row>>5)*(K/16) + (k>>4))*512 + ((k>>3)&1)*256 + (row&31)*8 + (k&7)
// wave fragment load for (rowgroup rg, kslice ks) = base + (rg*(K/16)+ks)*512 + lane*8
// = 64 lanes x 16 B contiguous (perfectly coalesced).

// ---------------------------------------------------------------------------
// pre_kernel: blocks 0..255 = hxhy via MFMA (w1 consumed directly, alpha/bias
// folded in epilogue; hy written in fragment layout); blocks 256..319 =
// weight prep (BN-fold w2/w3, cast w4; all written in fragment layout).
// ---------------------------------------------------------------------------
__global__ __launch_bounds__(256)
void pre_kernel(
    const float* __restrict__ x, const float* __restrict__ y,
    const float* __restrict__ w1, const float* __restrict__ b1,
    const float* __restrict__ g1, const float* __restrict__ be1,
    const float* __restrict__ m1, const float* __restrict__ v1,
    const float* __restrict__ w2, const float* __restrict__ b2,
    const float* __restrict__ g2, const float* __restrict__ be2,
    const float* __restrict__ m2, const float* __restrict__ v2,
    const float* __restrict__ w3, const float* __restrict__ b3,
    const float* __restrict__ g3, const float* __restrict__ be3,
    const float* __restrict__ m3, const float* __restrict__ v3,
    const float* __restrict__ w4,
    _Float16* __restrict__ hxh, _Float16* __restrict__ hyh,
    _Float16* __restrict__ w2h, _Float16* __restrict__ w3h,
    _Float16* __restrict__ w4h,
    float* __restrict__ b2f, float* __restrict__ b3f)
{
    const int t = threadIdx.x;

    if (blockIdx.x >= 256) {
        // ---------------- prep part (fragment-scattered writes) ----------------
        int tid = (blockIdx.x - 256) * 256 + t;
        const int nth = 64 * 256;
        for (int idx = tid; idx < 256 * 512; idx += nth) {
            int n = idx >> 9, k = idx & 511;
            float a = g2[n] * rsqrtf(v2[n] + EPS);
            int addr = ((n >> 5) * 32 + (k >> 4)) * 512 + ((k >> 3) & 1) * 256 + (n & 31) * 8 + (k & 7);
            w2h[addr] = (_Float16)(a * w2[idx]);
        }
        for (int idx = tid; idx < 128 * 256; idx += nth) {
            int n = idx >> 8, k = idx & 255;
            float a = g3[n] * rsqrtf(v3[n] + EPS);
            int addr = ((n >> 5) * 16 + (k >> 4)) * 512 + ((k >> 3) & 1) * 256 + (n & 31) * 8 + (k & 7);
            w3h[addr] = (_Float16)(a * w3[idx]);
        }
        for (int idx = tid; idx < 64 * 128; idx += nth) {
            int n = idx >> 7, k = idx & 127;
            int addr = ((n >> 5) * 8 + (k >> 4)) * 512 + ((k >> 3) & 1) * 256 + (n & 31) * 8 + (k & 7);
            w4h[addr] = (_Float16)w4[idx];
        }
        if (tid < 256) {
            float a = g2[tid] * rsqrtf(v2[tid] + EPS);
            b2f[tid] = a * b2[tid] + be2[tid] - m2[tid] * a;
        } else if (tid < 384) {
            int n = tid - 256;
            float a = g3[n] * rsqrtf(v3[n] + EPS);
            b3f[n] = a * b3[n] + be3[n] - m3[n] * a;
        }
        return;
    }

    // ---------------- hxhy part ----------------
    // bid: rg = 32-row group (32), ng = 128-col group (4), which = x/y (2)
    const int rg = blockIdx.x & 31;
    const int ng = (blockIdx.x >> 5) & 3;
    const int which = blockIdx.x >> 7;

    constexpr int LDA = 136;  // 272 B row stride
    __shared__ _Float16 sh[32 * 136 + 128 * 136] __attribute__((aligned(16)));
    _Float16* xa = sh;                 // [32][136]
    _Float16* wb = sh + 32 * 136;      // [128][136]

    const int rowbase = rg * 32;
    const float* src = which ? y : x;

    // stage A: 32 rows x 128 f32 -> f16
#pragma unroll
    for (int p = 0; p < 4; ++p) {
        int c = p * 256 + t;               // 0..1023 float4-chunks
        int r = c >> 5, fo = (c & 31) * 4;
        f32x4v v = *(const f32x4v*)(src + (size_t)(rowbase + r) * 128 + fo);
        half4 h; h[0] = (_Float16)v[0]; h[1] = (_Float16)v[1];
        h[2] = (_Float16)v[2]; h[3] = (_Float16)v[3];
        *(half4*)(xa + r * LDA + fo) = h;
    }
    // stage B: 128 n-rows x 128 k f32 -> f16 (w1 row-major, k-offset by which)
#pragma unroll
    for (int p = 0; p < 16; ++p) {
        int c = p * 256 + t;               // 0..4095
        int n = c >> 5, fo = (c & 31) * 4;
        f32x4v v = *(const f32x4v*)(w1 + (size_t)(ng * 128 + n) * 256 + which * 128 + fo);
        half4 h; h[0] = (_Float16)v[0]; h[1] = (_Float16)v[1];
        h[2] = (_Float16)v[2]; h[3] = (_Float16)v[3];
        *(half4*)(wb + n * LDA + fo) = h;
    }
    __syncthreads();

    const int wid = t >> 6;
    const int l = t & 63;
    const int l31 = l & 31, lh = l >> 5;

    f32x16 acc = (f32x16)0.f;
#pragma unroll
    for (int kc = 0; kc < 8; ++kc) {
        half8 af = *(const half8*)(xa + l31 * LDA + kc * 16 + lh * 8);
        half8 bf = *(const half8*)(wb + (wid * 32 + l31) * LDA + kc * 16 + lh * 8);
        acc = __builtin_amdgcn_mfma_f32_32x32x16_f16(af, bf, acc, 0, 0, 0);
    }

    const int n = ng * 128 + wid * 32 + l31;
    float alpha = g1[n] * rsqrtf(v1[n] + EPS);
    if (which == 0) {
        float bias = alpha * b1[n] + be1[n] - m1[n] * alpha;
#pragma unroll
        for (int r = 0; r < 16; ++r) {
            int m = (r & 3) + 8 * (r >> 2) + 4 * lh;
            hxh[(size_t)(rowbase + m) * 512 + n] = (_Float16)(alpha * acc[r] + bias);
        }
    } else {
        // hy in fragment layout (per-b region of 65536 halves; K16=32)
        const int ks = n >> 4, lhh = (n >> 3) & 1, c = n & 7;
#pragma unroll
        for (int r = 0; r < 16; ++r) {
            int m = (r & 3) + 8 * (r >> 2) + 4 * lh;
            int R = rowbase + m;                // global row = b*128 + j
            int bb = R >> 7, j = R & 127;
            int addr = bb * 65536 + ((j >> 5) * 32 + ks) * 512 + lhh * 256 + (j & 31) * 8 + c;
            hyh[addr] = (_Float16)(alpha * acc[r]);
        }
    }
}

// ---------------------------------------------------------------------------
// fused: one block per (b,i). M=128 (all j), 512->256->128->64 MLP with
// 32x32x16 f16 MFMA, then s=sum_j e, out[j]=e[j]·s. 512 threads = 8 waves.
// L2 phase: 4M x 2N wave grid (row-group assembled by 2 waves -> half relu
// VALU + half hy loads vs 2x4), A/B fragments streamed directly from global
// (pre-swizzled fragment layout, L2-resident), bias folded into MFMA C-init.
// Depth-1 pipeline with NAMED regs + unroll 2 (spill-safe: round-7 full
// unroll spilled to scratch, 528 MB writes). LDS 71168 B -> 2 blocks/CU.
// ---------------------------------------------------------------------------
__global__ __launch_bounds__(512, 4)
void fused_kernel(
    const _Float16* __restrict__ hxh, const _Float16* __restrict__ hyh,
    const _Float16* __restrict__ w2h, const _Float16* __restrict__ w3h,
    const _Float16* __restrict__ w4h,
    const float* __restrict__ b2f, const float* __restrict__ b3f,
    const float* __restrict__ b4,
    float* __restrict__ out)
{
    constexpr int LD2 = 264;  // a2 row stride (halves), 528 B (proven 0-conflict)
    constexpr int LD3 = 136;  // a3 row stride (halves), 272 B
    constexpr int LDE = 68;   // es row stride (f32), 272 B

    __shared__ char smem[3584 + 67584] __attribute__((aligned(16)));
    _Float16* hxs = (_Float16*)smem;             // [512] f16   1024 B
    float* spart  = (float*)(smem + 1024);       // [8][64]     2048 B
    float* ss     = (float*)(smem + 3072);       // [64]         256 B
    char* R1 = smem + 3584;
    _Float16* a2  = (_Float16*)R1;               // [128][264] 67584 B (after L2)
    _Float16* a3  = (_Float16*)R1;               // [128][136] (after L3)
    float*    es  = (float*)R1;                  // [128][68]  (after L4)

    const int b = blockIdx.x >> 7;
    const int i = blockIdx.x & 127;
    const int t = threadIdx.x;
    const int wid = t >> 6;
    const int l   = t & 63;
    const int l31 = l & 31;
    const int lh  = l >> 5;

    if (t < 64)
        *(half8*)(hxs + t * 8) = *(const half8*)(hxh + (size_t)(b * 128 + i) * 512 + t * 8);
    __syncthreads();

    // ---------------- layer 2: [128x512] @ [256x512]^T, 4M x 2N ----------------
    const int wm2 = wid >> 1;                    // 0..3 row-group (32 rows)
    const int wn2 = wid & 1;                     // 0..1 col-half (128 cols)

    const _Float16* pa = hyh + (size_t)b * 65536 + (size_t)(wm2 * 32) * 512 + l * 8;
    const _Float16* pb = w2h + (size_t)(wn2 * 4) * 32 * 512 + l * 8;

    f32x16 c0 = (f32x16)(b2f[wn2 * 128 +  0 + l31]);   // bias C-init
    f32x16 c1 = (f32x16)(b2f[wn2 * 128 + 32 + l31]);
    f32x16 c2 = (f32x16)(b2f[wn2 * 128 + 64 + l31]);
    f32x16 c3 = (f32x16)(b2f[wn2 * 128 + 96 + l31]);

    half8 A0, B00, B01, B02, B03;                // buffer 0 (named, spill-safe)
    half8 A1, B10, B11, B12, B13;                // buffer 1

    auto LD0 = [&](int ks) {
        A0  = *(const half8*)(pa + (size_t)ks * 512);
        B00 = *(const half8*)(pb + (size_t)(0 * 32 + ks) * 512);
        B01 = *(const half8*)(pb + (size_t)(1 * 32 + ks) * 512);
        B02 = *(const half8*)(pb + (size_t)(2 * 32 + ks) * 512);
        B03 = *(const half8*)(pb + (size_t)(3 * 32 + ks) * 512);
    };
    auto LD1 = [&](int ks) {
        A1  = *(const half8*)(pa + (size_t)ks * 512);
        B10 = *(const half8*)(pb + (size_t)(0 * 32 + ks) * 512);
        B11 = *(const half8*)(pb + (size_t)(1 * 32 + ks) * 512);
        B12 = *(const half8*)(pb + (size_t)(2 * 32 + ks) * 512);
        B13 = *(const half8*)(pb + (size_t)(3 * 32 + ks) * 512);
    };
    auto STEP0 = [&](int ks) {
        half8 rx = *(const half8*)(hxs + ks * 16 + lh * 8);
        half8 s = A0 + rx;
        half8 af;
#pragma unroll
        for (int c = 0; c < 8; ++c)
            af[c] = s[c] > (_Float16)0.f ? s[c] : (_Float16)0.f;
        c0 = __builtin_amdgcn_mfma_f32_32x32x16_f16(af, B00, c0, 0, 0, 0);
        c1 = __builtin_amdgcn_mfma_f32_32x32x16_f16(af, B01, c1, 0, 0, 0);
        c2 = __builtin_amdgcn_mfma_f32_32x32x16_f16(af, B02, c2, 0, 0, 0);
        c3 = __builtin_amdgcn_mfma_f32_32x32x16_f16(af, B03, c3, 0, 0, 0);
    };
    auto STEP1 = [&](int ks) {
        half8 rx = *(const half8*)(hxs + ks * 16 + lh * 8);
        half8 s = A1 + rx;
        half8 af;
#pragma unroll
        for (int c = 0; c < 8; ++c)
            af[c] = s[c] > (_Float16)0.f ? s[c] : (_Float16)0.f;
        c0 = __builtin_amdgcn_mfma_f32_32x32x16_f16(af, B10, c0, 0, 0, 0);
        c1 = __builtin_amdgcn_mfma_f32_32x32x16_f16(af, B11, c1, 0, 0, 0);
        c2 = __builtin_amdgcn_mfma_f32_32x32x16_f16(af, B12, c2, 0, 0, 0);
        c3 = __builtin_amdgcn_mfma_f32_32x32x16_f16(af, B13, c3, 0, 0, 0);
    };

    LD0(0);
#pragma unroll 2
    for (int ks = 0; ks < 32; ks += 2) {
        if (ks + 1 < 32) LD1(ks + 1);
        STEP0(ks);
        if (ks + 2 < 32) LD0(ks + 2);
        if (ks + 1 < 32) STEP1(ks + 1);
    }

    // epilogue -> a2 (fp16, relu); bias already in acc
#pragma unroll
    for (int r = 0; r < 16; ++r) {
        int m = wm2 * 32 + (r & 3) + 8 * (r >> 2) + 4 * lh;
        a2[m * LD2 + wn2 * 128 +  0 + l31] = (_Float16)fmaxf(c0[r], 0.f);
        a2[m * LD2 + wn2 * 128 + 32 + l31] = (_Float16)fmaxf(c1[r], 0.f);
        a2[m * LD2 + wn2 * 128 + 64 + l31] = (_Float16)fmaxf(c2[r], 0.f);
        a2[m * LD2 + wn2 * 128 + 96 + l31] = (_Float16)fmaxf(c3[r], 0.f);
    }
    __syncthreads();

    // ---------------- layer 3: [128x256] @ [128x256]^T, B = global fragments ----
    const int wm = wid >> 2, wn = wid & 3;       // 2 x 4 wave grid
    f32x16 acc3[2];
    {
        float b3v = b3f[wn * 32 + l31];          // bias C-init
        acc3[0] = (f32x16)b3v;
        acc3[1] = (f32x16)b3v;
    }
#pragma unroll 8
    for (int kc = 0; kc < 16; ++kc) {
        half8 bfr = *(const half8*)(w3h + (wn * 16 + kc) * 512 + l * 8);
        half8 af0 = *(const half8*)(a2 + (wm * 64 + l31) * LD2 + kc * 16 + lh * 8);
        half8 af1 = *(const half8*)(a2 + (wm * 64 + 32 + l31) * LD2 + kc * 16 + lh * 8);
        acc3[0] = __builtin_amdgcn_mfma_f32_32x32x16_f16(af0, bfr, acc3[0], 0, 0, 0);
        acc3[1] = __builtin_amdgcn_mfma_f32_32x32x16_f16(af1, bfr, acc3[1], 0, 0, 0);
    }
    __syncthreads();
#pragma unroll
    for (int mt = 0; mt < 2; ++mt)
#pragma unroll
        for (int r = 0; r < 16; ++r) {
            int m = wm * 64 + mt * 32 + (r & 3) + 8 * (r >> 2) + 4 * lh;
            a3[m * LD3 + wn * 32 + l31] = (_Float16)fmaxf(acc3[mt][r], 0.f);
        }
    __syncthreads();

    // ---------------- layer 4: [128x128] @ [64x128]^T, regrid 4x2 ----------
    const int wm4 = wid >> 1, wn4 = wid & 1;
    f32x16 acc4 = (f32x16)(b4[wn4 * 32 + l31]);  // bias C-init
#pragma unroll
    for (int kc = 0; kc < 8; ++kc) {
        half8 afr = *(const half8*)(a3 + (wm4 * 32 + l31) * LD3 + kc * 16 + lh * 8);
        half8 bfr = *(const half8*)(w4h + (wn4 * 8 + kc) * 512 + l * 8);
        acc4 = __builtin_amdgcn_mfma_f32_32x32x16_f16(afr, bfr, acc4, 0, 0, 0);
    }
    __syncthreads();  // a3 reads done before es overwrites it
#pragma unroll
    for (int r = 0; r < 16; ++r) {
        int m = wm4 * 32 + (r & 3) + 8 * (r >> 2) + 4 * lh;
        es[m * LDE + wn4 * 32 + l31] = acc4[r];
    }
    __syncthreads();

    // ---------------- s = sum_j e ; out[j] = sum_k e[j][k]*s[k] ------------
    {
        float sv = 0.f;
#pragma unroll
        for (int jj = 0; jj < 16; ++jj) sv += es[(wid + jj * 8) * LDE + l];
        spart[wid * 64 + l] = sv;
    }
    __syncthreads();
    if (t < 64) {
        float s2 = 0.f;
#pragma unroll
        for (int r = 0; r < 8; ++r) s2 += spart[r * 64 + t];
        ss[t] = s2;
    }
    __syncthreads();
    {
        const int j = t >> 2, q = t & 3;
        float p = 0.f;
#pragma unroll
        for (int c = 0; c < 16; ++c) {
            int k = q + 4 * c;               // k-interleaved: 2 lanes/bank
            p += es[j * LDE + k] * ss[k];
        }
        p += __shfl_xor(p, 1);
        p += __shfl_xor(p, 2);
        if (q == 0) out[(size_t)(b * 128 + i) * 128 + j] = p;
    }
}

// ---------------------------------------------------------------------------
extern "C" void kernel_launch(void* const* d_in, const int* in_sizes, int n_in,
                              void* d_out, int out_size, void* d_ws, size_t ws_size,
                              hipStream_t stream)
{
    (void)in_sizes; (void)n_in; (void)out_size; (void)ws_size;

    const float* x   = (const float*)d_in[0];
    const float* y   = (const float*)d_in[1];
    const float* w1  = (const float*)d_in[2];
    const float* b1  = (const float*)d_in[3];
    const float* g1  = (const float*)d_in[4];
    const float* be1 = (const float*)d_in[5];
    const float* m1  = (const float*)d_in[6];
    const float* v1  = (const float*)d_in[7];
    const float* w2  = (const float*)d_in[8];
    const float* b2  = (const float*)d_in[9];
    const float* g2  = (const float*)d_in[10];
    const float* be2 = (const float*)d_in[11];
    const float* m2  = (const float*)d_in[12];
    const float* v2  = (const float*)d_in[13];
    const float* w3  = (const float*)d_in[14];
    const float* b3  = (const float*)d_in[15];
    const float* g3  = (const float*)d_in[16];
    const float* be3 = (const float*)d_in[17];
    const float* m3  = (const float*)d_in[18];
    const float* v3  = (const float*)d_in[19];
    const float* w4  = (const float*)d_in[20];
    const float* b4  = (const float*)d_in[21];
    float* out = (float*)d_out;

    // workspace layout (~2.44 MB)
    float* b2f = (float*)d_ws;                 // 256 f32
    float* b3f = b2f + 256;                    // 128 f32
    _Float16* w2h = (_Float16*)(b3f + 128);    // 131072 f16 (fragment layout)
    _Float16* w3h = w2h + 131072;              // 32768 f16  (fragment layout)
    _Float16* w4h = w3h + 32768;               // 8192 f16   (fragment layout)
    _Float16* hxh = w4h + 8192;                // 524288 f16 (linear)
    _Float16* hyh = hxh + 524288;              // 524288 f16 (fragment layout per b)

    hipLaunchKernelGGL(pre_kernel, dim3(320), dim3(256), 0, stream,
                       x, y, w1, b1, g1, be1, m1, v1,
                       w2, b2, g2, be2, m2, v2,
                       w3, b3, g3, be3, m3, v3,
                       w4,
                       hxh, hyh, w2h, w3h, w4h, b2f, b3f);

    hipLaunchKernelGGL(fused_kernel, dim3(1024), dim3(512), 0, stream,
                       hxh, hyh, w2h, w3h, w4h, b2f, b3f, b4, out);
}

// Round 9
// 67.206 us; speedup vs baseline: 2.8909x; 1.0243x over previous
//
#include <hip/hip_runtime.h>

#define EPS 1e-5f

typedef _Float16 half8 __attribute__((ext_vector_type(8)));
typedef _Float16 half4 __attribute__((ext_vector_type(4)));
typedef float f32x16 __attribute__((ext_vector_type(16)));
typedef float f32x4v __attribute__((ext_vector_type(4)));

// Fragment layout for an [R x K] f16 matrix consumed as 32-row MFMA operand:
// element (row, k) -> ((row>>5)*(K/16) + (k>>4))*512 + ((k>>3)&1)*256 + (row&31)*8 + (k&7)
// wave fragment load for (rowgroup rg, kslice ks) = base + (rg*(K/16)+ks)*512 + lane*8
// = 64 lanes x 16 B contiguous (perfectly coalesced).

// ---------------------------------------------------------------------------
// pre_kernel: blocks 0..255 = hxhy via MFMA (w1 consumed directly, alpha/bias
// folded in epilogue; hy written in fragment layout); blocks 256..319 =
// weight prep (BN-fold w2/w3, cast w4; all written in fragment layout).
// ---------------------------------------------------------------------------
__global__ __launch_bounds__(256)
void pre_kernel(
    const float* __restrict__ x, const float* __restrict__ y,
    const float* __restrict__ w1, const float* __restrict__ b1,
    const float* __restrict__ g1, const float* __restrict__ be1,
    const float* __restrict__ m1, const float* __restrict__ v1,
    const float* __restrict__ w2, const float* __restrict__ b2,
    const float* __restrict__ g2, const float* __restrict__ be2,
    const float* __restrict__ m2, const float* __restrict__ v2,
    const float* __restrict__ w3, const float* __restrict__ b3,
    const float* __restrict__ g3, const float* __restrict__ be3,
    const float* __restrict__ m3, const float* __restrict__ v3,
    const float* __restrict__ w4,
    _Float16* __restrict__ hxh, _Float16* __restrict__ hyh,
    _Float16* __restrict__ w2h, _Float16* __restrict__ w3h,
    _Float16* __restrict__ w4h,
    float* __restrict__ b2f, float* __restrict__ b3f)
{
    const int t = threadIdx.x;

    if (blockIdx.x >= 256) {
        // ---------------- prep part (fragment-scattered writes) ----------------
        int tid = (blockIdx.x - 256) * 256 + t;
        const int nth = 64 * 256;
        for (int idx = tid; idx < 256 * 512; idx += nth) {
            int n = idx >> 9, k = idx & 511;
            float a = g2[n] * rsqrtf(v2[n] + EPS);
            int addr = ((n >> 5) * 32 + (k >> 4)) * 512 + ((k >> 3) & 1) * 256 + (n & 31) * 8 + (k & 7);
            w2h[addr] = (_Float16)(a * w2[idx]);
        }
        for (int idx = tid; idx < 128 * 256; idx += nth) {
            int n = idx >> 8, k = idx & 255;
            float a = g3[n] * rsqrtf(v3[n] + EPS);
            int addr = ((n >> 5) * 16 + (k >> 4)) * 512 + ((k >> 3) & 1) * 256 + (n & 31) * 8 + (k & 7);
            w3h[addr] = (_Float16)(a * w3[idx]);
        }
        for (int idx = tid; idx < 64 * 128; idx += nth) {
            int n = idx >> 7, k = idx & 127;
            int addr = ((n >> 5) * 8 + (k >> 4)) * 512 + ((k >> 3) & 1) * 256 + (n & 31) * 8 + (k & 7);
            w4h[addr] = (_Float16)w4[idx];
        }
        if (tid < 256) {
            float a = g2[tid] * rsqrtf(v2[tid] + EPS);
            b2f[tid] = a * b2[tid] + be2[tid] - m2[tid] * a;
        } else if (tid < 384) {
            int n = tid - 256;
            float a = g3[n] * rsqrtf(v3[n] + EPS);
            b3f[n] = a * b3[n] + be3[n] - m3[n] * a;
        }
        return;
    }

    // ---------------- hxhy part ----------------
    // bid: rg = 32-row group (32), ng = 128-col group (4), which = x/y (2)
    const int rg = blockIdx.x & 31;
    const int ng = (blockIdx.x >> 5) & 3;
    const int which = blockIdx.x >> 7;

    constexpr int LDA = 136;  // 272 B row stride
    __shared__ _Float16 sh[32 * 136 + 128 * 136] __attribute__((aligned(16)));
    _Float16* xa = sh;                 // [32][136]
    _Float16* wb = sh + 32 * 136;      // [128][136]

    const int rowbase = rg * 32;
    const float* src = which ? y : x;

    // stage A: 32 rows x 128 f32 -> f16
#pragma unroll
    for (int p = 0; p < 4; ++p) {
        int c = p * 256 + t;               // 0..1023 float4-chunks
        int r = c >> 5, fo = (c & 31) * 4;
        f32x4v v = *(const f32x4v*)(src + (size_t)(rowbase + r) * 128 + fo);
        half4 h; h[0] = (_Float16)v[0]; h[1] = (_Float16)v[1];
        h[2] = (_Float16)v[2]; h[3] = (_Float16)v[3];
        *(half4*)(xa + r * LDA + fo) = h;
    }
    // stage B: 128 n-rows x 128 k f32 -> f16 (w1 row-major, k-offset by which)
#pragma unroll
    for (int p = 0; p < 16; ++p) {
        int c = p * 256 + t;               // 0..4095
        int n = c >> 5, fo = (c & 31) * 4;
        f32x4v v = *(const f32x4v*)(w1 + (size_t)(ng * 128 + n) * 256 + which * 128 + fo);
        half4 h; h[0] = (_Float16)v[0]; h[1] = (_Float16)v[1];
        h[2] = (_Float16)v[2]; h[3] = (_Float16)v[3];
        *(half4*)(wb + n * LDA + fo) = h;
    }
    __syncthreads();

    const int wid = t >> 6;
    const int l = t & 63;
    const int l31 = l & 31, lh = l >> 5;

    f32x16 acc = (f32x16)0.f;
#pragma unroll
    for (int kc = 0; kc < 8; ++kc) {
        half8 af = *(const half8*)(xa + l31 * LDA + kc * 16 + lh * 8);
        half8 bf = *(const half8*)(wb + (wid * 32 + l31) * LDA + kc * 16 + lh * 8);
        acc = __builtin_amdgcn_mfma_f32_32x32x16_f16(af, bf, acc, 0, 0, 0);
    }

    const int n = ng * 128 + wid * 32 + l31;
    float alpha = g1[n] * rsqrtf(v1[n] + EPS);
    if (which == 0) {
        float bias = alpha * b1[n] + be1[n] - m1[n] * alpha;
#pragma unroll
        for (int r = 0; r < 16; ++r) {
            int m = (r & 3) + 8 * (r >> 2) + 4 * lh;
            hxh[(size_t)(rowbase + m) * 512 + n] = (_Float16)(alpha * acc[r] + bias);
        }
    } else {
        // hy in fragment layout (per-b region of 65536 halves; K16=32)
        const int ks = n >> 4, lhh = (n >> 3) & 1, c = n & 7;
#pragma unroll
        for (int r = 0; r < 16; ++r) {
            int m = (r & 3) + 8 * (r >> 2) + 4 * lh;
            int R = rowbase + m;                // global row = b*128 + j
            int bb = R >> 7, j = R & 127;
            int addr = bb * 65536 + ((j >> 5) * 32 + ks) * 512 + lhh * 256 + (j & 31) * 8 + c;
            hyh[addr] = (_Float16)(alpha * acc[r]);
        }
    }
}

// ---------------------------------------------------------------------------
// fused: one block per (b, i-pair). Two i's share every A/B fragment load
// (hy/w2 identical across i; only broadcast hx differs) -> per-i load issue
// halves vs single-i. 8 waves (2M x 4N grid, 64x64 per wave per i), 8 f32x16
// accs (~200 regs -> 2 waves/SIMD, launch_bounds(512,2)). No barriers in the
// L2 k-loop (global-direct fragments). Tail phases = round-6 proven code,
// run twice (i1 accs stay live in registers through i0's tail).
// ---------------------------------------------------------------------------
__global__ __launch_bounds__(512, 2)
void fused_kernel(
    const _Float16* __restrict__ hxh, const _Float16* __restrict__ hyh,
    const _Float16* __restrict__ w2h, const _Float16* __restrict__ w3h,
    const _Float16* __restrict__ w4h,
    const float* __restrict__ b2f, const float* __restrict__ b3f,
    const float* __restrict__ b4,
    float* __restrict__ out)
{
    constexpr int LD2 = 264;  // a2 row stride (halves), 528 B (proven 0-conflict)
    constexpr int LD3 = 136;  // a3 row stride (halves), 272 B
    constexpr int LDE = 68;   // es row stride (f32), 272 B

    __shared__ char smem[4352 + 67584] __attribute__((aligned(16)));
    _Float16* hxs = (_Float16*)smem;             // [2][512] f16  2048 B
    float* spart  = (float*)(smem + 2048);       // [8][64]       2048 B
    float* ss     = (float*)(smem + 4096);       // [64]           256 B
    char* R1 = smem + 4352;
    _Float16* a2  = (_Float16*)R1;               // [128][264] 67584 B (after L2)
    _Float16* a3  = (_Float16*)R1;               // [128][136] (after L3)
    float*    es  = (float*)R1;                  // [128][68]  (after L4)

    const int b  = blockIdx.x >> 6;              // 0..7
    const int ip = blockIdx.x & 63;              // 0..63
    const int i0 = ip * 2;
    const int t = threadIdx.x;
    const int wid = t >> 6;
    const int l   = t & 63;
    const int l31 = l & 31;
    const int lh  = l >> 5;

    if (t < 128) {
        int iv = t >> 6;                         // 0,1
        *(half8*)(hxs + iv * 512 + (t & 63) * 8) =
            *(const half8*)(hxh + (size_t)(b * 128 + i0 + iv) * 512 + (t & 63) * 8);
    }
    __syncthreads();

    // ---------------- layer 2: [128x512] @ [256x512]^T, 2M x 4N, 2 i ----------
    const int wm = wid >> 2, wn = wid & 3;

    const _Float16* pa0 = hyh + (size_t)b * 65536 + (size_t)(2 * wm) * 32 * 512 + l * 8;
    const _Float16* pa1 = pa0 + 32 * 512;
    const _Float16* pb0 = w2h + (size_t)(2 * wn) * 32 * 512 + l * 8;
    const _Float16* pb1 = pb0 + 32 * 512;

    const float bb0 = b2f[wn * 64 + l31];
    const float bb1 = b2f[wn * 64 + 32 + l31];
    f32x16 d00 = (f32x16)bb0, d01 = (f32x16)bb1;   // i0: (m0,n0) (m0,n1)
    f32x16 d10 = (f32x16)bb0, d11 = (f32x16)bb1;   // i0: (m1,n0) (m1,n1)
    f32x16 e00 = (f32x16)bb0, e01 = (f32x16)bb1;   // i1
    f32x16 e10 = (f32x16)bb0, e11 = (f32x16)bb1;

    half8 A00, A01, B00, B01;                    // set 0 (named, spill-safe)
    half8 A10, A11, B10, B11;                    // set 1

    auto LD0 = [&](int ks) {
        A00 = *(const half8*)(pa0 + (size_t)ks * 512);
        A01 = *(const half8*)(pa1 + (size_t)ks * 512);
        B00 = *(const half8*)(pb0 + (size_t)ks * 512);
        B01 = *(const half8*)(pb1 + (size_t)ks * 512);
    };
    auto LD1 = [&](int ks) {
        A10 = *(const half8*)(pa0 + (size_t)ks * 512);
        A11 = *(const half8*)(pa1 + (size_t)ks * 512);
        B10 = *(const half8*)(pb0 + (size_t)ks * 512);
        B11 = *(const half8*)(pb1 + (size_t)ks * 512);
    };
    auto RELU = [&](half8 a, half8 rx) {
        half8 s = a + rx;
        half8 af;
#pragma unroll
        for (int c = 0; c < 8; ++c)
            af[c] = s[c] > (_Float16)0.f ? s[c] : (_Float16)0.f;
        return af;
    };
    auto STEP0 = [&](int ks) {
        half8 rx0 = *(const half8*)(hxs + ks * 16 + lh * 8);
        half8 rx1 = *(const half8*)(hxs + 512 + ks * 16 + lh * 8);
        half8 af;
        af = RELU(A00, rx0);
        d00 = __builtin_amdgcn_mfma_f32_32x32x16_f16(af, B00, d00, 0, 0, 0);
        d01 = __builtin_amdgcn_mfma_f32_32x32x16_f16(af, B01, d01, 0, 0, 0);
        af = RELU(A01, rx0);
        d10 = __builtin_amdgcn_mfma_f32_32x32x16_f16(af, B00, d10, 0, 0, 0);
        d11 = __builtin_amdgcn_mfma_f32_32x32x16_f16(af, B01, d11, 0, 0, 0);
        af = RELU(A00, rx1);
        e00 = __builtin_amdgcn_mfma_f32_32x32x16_f16(af, B00, e00, 0, 0, 0);
        e01 = __builtin_amdgcn_mfma_f32_32x32x16_f16(af, B01, e01, 0, 0, 0);
        af = RELU(A01, rx1);
        e10 = __builtin_amdgcn_mfma_f32_32x32x16_f16(af, B00, e10, 0, 0, 0);
        e11 = __builtin_amdgcn_mfma_f32_32x32x16_f16(af, B01, e11, 0, 0, 0);
    };
    auto STEP1 = [&](int ks) {
        half8 rx0 = *(const half8*)(hxs + ks * 16 + lh * 8);
        half8 rx1 = *(const half8*)(hxs + 512 + ks * 16 + lh * 8);
        half8 af;
        af = RELU(A10, rx0);
        d00 = __builtin_amdgcn_mfma_f32_32x32x16_f16(af, B10, d00, 0, 0, 0);
        d01 = __builtin_amdgcn_mfma_f32_32x32x16_f16(af, B11, d01, 0, 0, 0);
        af = RELU(A11, rx0);
        d10 = __builtin_amdgcn_mfma_f32_32x32x16_f16(af, B10, d10, 0, 0, 0);
        d11 = __builtin_amdgcn_mfma_f32_32x32x16_f16(af, B11, d11, 0, 0, 0);
        af = RELU(A10, rx1);
        e00 = __builtin_amdgcn_mfma_f32_32x32x16_f16(af, B10, e00, 0, 0, 0);
        e01 = __builtin_amdgcn_mfma_f32_32x32x16_f16(af, B11, e01, 0, 0, 0);
        af = RELU(A11, rx1);
        e10 = __builtin_amdgcn_mfma_f32_32x32x16_f16(af, B10, e10, 0, 0, 0);
        e11 = __builtin_amdgcn_mfma_f32_32x32x16_f16(af, B11, e11, 0, 0, 0);
    };

    LD0(0);
#pragma unroll 2
    for (int ks = 0; ks < 32; ks += 2) {
        if (ks + 1 < 32) LD1(ks + 1);
        STEP0(ks);
        if (ks + 2 < 32) LD0(ks + 2);
        if (ks + 1 < 32) STEP1(ks + 1);
    }

    // ---------------- tail (L2-epilogue, L3, L4, reduction) x 2 i -----------
    auto TAIL = [&](const f32x16& a00, const f32x16& a01,
                    const f32x16& a10, const f32x16& a11, int iv) {
        // epilogue -> a2 (fp16, relu); bias already in acc
#pragma unroll
        for (int r = 0; r < 16; ++r) {
            int m = wm * 64 + (r & 3) + 8 * (r >> 2) + 4 * lh;
            a2[m * LD2 + wn * 64 + l31]               = (_Float16)fmaxf(a00[r], 0.f);
            a2[m * LD2 + wn * 64 + 32 + l31]          = (_Float16)fmaxf(a01[r], 0.f);
            a2[(m + 32) * LD2 + wn * 64 + l31]        = (_Float16)fmaxf(a10[r], 0.f);
            a2[(m + 32) * LD2 + wn * 64 + 32 + l31]   = (_Float16)fmaxf(a11[r], 0.f);
        }
        __syncthreads();

        // layer 3: [128x256] @ [128x256]^T, B = global fragments
        f32x16 g0, g1;
        {
            float b3v = b3f[wn * 32 + l31];
            g0 = (f32x16)b3v;
            g1 = (f32x16)b3v;
        }
#pragma unroll 4
        for (int kc = 0; kc < 16; ++kc) {
            half8 bfr = *(const half8*)(w3h + (wn * 16 + kc) * 512 + l * 8);
            half8 af0 = *(const half8*)(a2 + (wm * 64 + l31) * LD2 + kc * 16 + lh * 8);
            half8 af1 = *(const half8*)(a2 + (wm * 64 + 32 + l31) * LD2 + kc * 16 + lh * 8);
            g0 = __builtin_amdgcn_mfma_f32_32x32x16_f16(af0, bfr, g0, 0, 0, 0);
            g1 = __builtin_amdgcn_mfma_f32_32x32x16_f16(af1, bfr, g1, 0, 0, 0);
        }
        __syncthreads();
#pragma unroll
        for (int mt = 0; mt < 2; ++mt)
#pragma unroll
            for (int r = 0; r < 16; ++r) {
                int m = wm * 64 + mt * 32 + (r & 3) + 8 * (r >> 2) + 4 * lh;
                a3[m * LD3 + wn * 32 + l31] = (_Float16)fmaxf(mt ? g1[r] : g0[r], 0.f);
            }
        __syncthreads();

        // layer 4: [128x128] @ [64x128]^T, regrid 4x2
        const int wm4 = wid >> 1, wn4 = wid & 1;
        f32x16 acc4 = (f32x16)(b4[wn4 * 32 + l31]);
#pragma unroll
        for (int kc = 0; kc < 8; ++kc) {
            half8 afr = *(const half8*)(a3 + (wm4 * 32 + l31) * LD3 + kc * 16 + lh * 8);
            half8 bfr = *(const half8*)(w4h + (wn4 * 8 + kc) * 512 + l * 8);
            acc4 = __builtin_amdgcn_mfma_f32_32x32x16_f16(afr, bfr, acc4, 0, 0, 0);
        }
        __syncthreads();  // a3 reads done before es overwrites it
#pragma unroll
        for (int r = 0; r < 16; ++r) {
            int m = wm4 * 32 + (r & 3) + 8 * (r >> 2) + 4 * lh;
            es[m * LDE + wn4 * 32 + l31] = acc4[r];
        }
        __syncthreads();

        // s = sum_j e ; out[j] = sum_k e[j][k]*s[k]
        {
            float sv = 0.f;
#pragma unroll
            for (int jj = 0; jj < 16; ++jj) sv += es[(wid + jj * 8) * LDE + l];
            spart[wid * 64 + l] = sv;
        }
        __syncthreads();
        if (t < 64) {
            float s2 = 0.f;
#pragma unroll
            for (int r = 0; r < 8; ++r) s2 += spart[r * 64 + t];
            ss[t] = s2;
        }
        __syncthreads();
        {
            const int j = t >> 2, q = t & 3;
            float p = 0.f;
#pragma unroll
            for (int c = 0; c < 16; ++c) {
                int k = q + 4 * c;               // k-interleaved: 2 lanes/bank
                p += es[j * LDE + k] * ss[k];
            }
            p += __shfl_xor(p, 1);
            p += __shfl_xor(p, 2);
            if (q == 0) out[(size_t)(b * 128 + iv) * 128 + j] = p;
        }
        __syncthreads();  // es reads done before next a2 write
    };

    TAIL(d00, d01, d10, d11, i0);
    TAIL(e00, e01, e10, e11, i0 + 1);
}

// ---------------------------------------------------------------------------
extern "C" void kernel_launch(void* const* d_in, const int* in_sizes, int n_in,
                              void* d_out, int out_size, void* d_ws, size_t ws_size,
                              hipStream_t stream)
{
    (void)in_sizes; (void)n_in; (void)out_size; (void)ws_size;

    const float* x   = (const float*)d_in[0];
    const float* y   = (const float*)d_in[1];
    const float* w1  = (const float*)d_in[2];
    const float* b1  = (const float*)d_in[3];
    const float* g1  = (const float*)d_in[4];
    const float* be1 = (const float*)d_in[5];
    const float* m1  = (const float*)d_in[6];
    const float* v1  = (const float*)d_in[7];
    const float* w2  = (const float*)d_in[8];
    const float* b2  = (const float*)d_in[9];
    const float* g2  = (const float*)d_in[10];
    const float* be2 = (const float*)d_in[11];
    const float* m2  = (const float*)d_in[12];
    const float* v2  = (const float*)d_in[13];
    const float* w3  = (const float*)d_in[14];
    const float* b3  = (const float*)d_in[15];
    const float* g3  = (const float*)d_in[16];
    const float* be3 = (const float*)d_in[17];
    const float* m3  = (const float*)d_in[18];
    const float* v3  = (const float*)d_in[19];
    const float* w4  = (const float*)d_in[20];
    const float* b4  = (const float*)d_in[21];
    float* out = (float*)d_out;

    // workspace layout (~2.44 MB)
    float* b2f = (float*)d_ws;                 // 256 f32
    float* b3f = b2f + 256;                    // 128 f32
    _Float16* w2h = (_Float16*)(b3f + 128);    // 131072 f16 (fragment layout)
    _Float16* w3h = w2h + 131072;              // 32768 f16  (fragment layout)
    _Float16* w4h = w3h + 32768;               // 8192 f16   (fragment layout)
    _Float16* hxh = w4h + 8192;                // 524288 f16 (linear)
    _Float16* hyh = hxh + 524288;              // 524288 f16 (fragment layout per b)

    hipLaunchKernelGGL(pre_kernel, dim3(320), dim3(256), 0, stream,
                       x, y, w1, b1, g1, be1, m1, v1,
                       w2, b2, g2, be2, m2, v2,
                       w3, b3, g3, be3, m3, v3,
                       w4,
                       hxh, hyh, w2h, w3h, w4h, b2f, b3f);

    hipLaunchKernelGGL(fused_kernel, dim3(512), dim3(512), 0, stream,
                       hxh, hyh, w2h, w3h, w4h, b2f, b3f, b4, out);
}